// Round 1
// baseline (167.900 us; speedup 1.0000x reference)
//
#include <hip/hip_runtime.h>
#include <hip/hip_bf16.h>
#include <stdint.h>

// QuantConv2d on MI355X: per-tensor symmetric int8-range quant + 3x3 conv via bf16 MFMA.
// Exactness: q values are small ints -> bf16 exact; fp32 accum of int products < 2^24 exact.

typedef short short8 __attribute__((ext_vector_type(8)));
typedef float f32x4  __attribute__((ext_vector_type(4)));

#define CIN   32
#define COUT  32
#define HH    224
#define WW    224
#define NB    8
#define KK    288            // 9 taps * 32 ci, k ordered (kh,kw,ci)
#define QMAXF 127.0f

#define RED_BLOCKS 1024

// ws layout (unsigned words): ws[0] = bits of max|x| (atomicMax), ws[1] = bits of w_scale,
// (short*)(ws+4) = pre-quantized weights as bf16, layout [COUT][KK], k=(kh*3+kw)*32+ci.

__global__ __launch_bounds__(256) void k_prep(const float* __restrict__ x, int n4,
                                              const float* __restrict__ wgt,
                                              unsigned* __restrict__ ws) {
    const int tid = threadIdx.x;
    __shared__ float red[4];
    if (blockIdx.x < RED_BLOCKS) {
        const float4* x4 = (const float4*)x;
        float m = 0.f;
        for (int i = blockIdx.x * 256 + tid; i < n4; i += RED_BLOCKS * 256) {
            float4 v = x4[i];
            m = fmaxf(m, fmaxf(fmaxf(fabsf(v.x), fabsf(v.y)), fmaxf(fabsf(v.z), fabsf(v.w))));
        }
        #pragma unroll
        for (int off = 32; off >= 1; off >>= 1) m = fmaxf(m, __shfl_xor(m, off));
        if ((tid & 63) == 0) red[tid >> 6] = m;
        __syncthreads();
        if (tid == 0) {
            m = fmaxf(fmaxf(red[0], red[1]), fmaxf(red[2], red[3]));
            atomicMax(ws, __float_as_uint(m));   // all values >= 0: uint order == float order
        }
    } else {
        // single block: reduce max|w|, then pre-quantize weights to bf16 in ws.
        float m = 0.f;
        for (int i = tid; i < COUT * CIN * 9; i += 256) m = fmaxf(m, fabsf(wgt[i]));
        #pragma unroll
        for (int off = 32; off >= 1; off >>= 1) m = fmaxf(m, __shfl_xor(m, off));
        if ((tid & 63) == 0) red[tid >> 6] = m;
        __syncthreads();
        const float mw = fmaxf(fmaxf(red[0], red[1]), fmaxf(red[2], red[3]));
        const float wscale = mw / QMAXF;
        if (tid == 0) ws[1] = __float_as_uint(wscale);
        short* qw = (short*)(ws + 4);
        for (int e = tid; e < COUT * KK; e += 256) {
            const int co = e / KK, k = e % KK;
            const int t = k >> 5, ci = k & 31;
            const int kh = t / 3, kw = t % 3;
            const float v = wgt[((co * CIN + ci) * 3 + kh) * 3 + kw];
            float q = rintf(v / wscale);                  // IEEE div + round-half-even == jnp
            q = fminf(fmaxf(q, -QMAXF), QMAXF);
            qw[e] = (short)(__float_as_uint(q) >> 16);    // ints <=127: exact bf16 truncation
        }
    }
}

#define RT  4          // output rows per block
#define WT  32         // output cols per block
#define XR  (RT + 2)   // 6 staged rows (halo)
#define XW  (WT + 2)   // 34 staged cols (halo)
#define CIP 40         // padded ci stride in shorts: 80 B -> 16B-aligned b128, ~2-way banks

__global__ __launch_bounds__(256) void k_conv(const float* __restrict__ x,
                                              const float* __restrict__ bias,
                                              const unsigned* __restrict__ ws,
                                              float* __restrict__ out) {
    __shared__ __align__(16) short xs[XR * XW * CIP];   // 16320 B
    __shared__ __align__(16) short a_lds[COUT * KK];    // 18432 B

    const int tid = threadIdx.x;
    const int bid = blockIdx.x;
    const int b   = bid / (56 * 7);
    const int rem = bid % (56 * 7);
    const int h0  = (rem / 7) * RT;
    const int w0  = (rem % 7) * WT;

    const float xscale = __uint_as_float(ws[0]) / QMAXF;
    const float wscale = __uint_as_float(ws[1]);
    const float s = xscale * wscale;

    // stage pre-quantized A (bf16 shorts), coalesced int copies
    {
        const int* qwi = (const int*)(ws + 4);
        int* ali = (int*)a_lds;
        #pragma unroll
        for (int i = 0; i < 18; ++i) ali[tid + 256 * i] = qwi[tid + 256 * i];
    }

    // stage x patch: quantize fp32 -> bf16 int, layout [row][w][ci] ci-innermost
    for (int i = 0; i < 26; ++i) {
        const int e = tid + 256 * i;
        if (e < XR * XW * CIN) {
            const int wl = e % XW;
            const int q2 = e / XW;
            const int ci = q2 & 31;
            const int r  = q2 >> 5;
            const int h  = h0 - 1 + r;
            const int wg = w0 - 1 + wl;
            float v = 0.f;
            if ((unsigned)h < HH && (unsigned)wg < WW)
                v = x[((b * CIN + ci) * HH + h) * WW + wg];
            float qv = rintf(v / xscale);                 // exact IEEE div, half-even
            qv = fminf(fmaxf(qv, -QMAXF), QMAXF);
            xs[(r * XW + wl) * CIP + ci] = (short)(__float_as_uint(qv) >> 16);
        }
    }
    __syncthreads();

    const int lane = tid & 63;
    const int wr   = tid >> 6;     // wave id == local output row
    const int col  = lane & 15;    // MFMA N (pixel) / M-row-low for A reads
    const int kgrp = lane >> 4;    // k-group 0..3

    // hoist all A fragments: A[m-tile][k] layout row-major [co][KK]
    short8 afr[9][2];
    #pragma unroll
    for (int t = 0; t < 9; ++t)
        #pragma unroll
        for (int m = 0; m < 2; ++m)
            afr[t][m] = *(const short8*)&a_lds[(m * 16 + col) * KK + t * 32 + kgrp * 8];

    const f32x4 zero = {0.f, 0.f, 0.f, 0.f};
    f32x4 acc[2][2] = {{zero, zero}, {zero, zero}};

    #pragma unroll
    for (int t = 0; t < 9; ++t) {
        const int kh = t / 3, kw = t % 3;
        short8 bfr[2];
        #pragma unroll
        for (int nt = 0; nt < 2; ++nt)
            bfr[nt] = *(const short8*)&xs[((wr + kh) * XW + (nt * 16 + col + kw)) * CIP + kgrp * 8];
        #pragma unroll
        for (int m = 0; m < 2; ++m)
            #pragma unroll
            for (int nt = 0; nt < 2; ++nt)
                acc[m][nt] = __builtin_amdgcn_mfma_f32_16x16x32_bf16(afr[t][m], bfr[nt], acc[m][nt], 0, 0, 0);
    }

    // epilogue: dequant + bias; D layout: row = (lane>>4)*4 + reg, col = lane&15
    const int row4 = kgrp * 4;
    const int hout = h0 + wr;
    #pragma unroll
    for (int m = 0; m < 2; ++m) {
        #pragma unroll
        for (int r = 0; r < 4; ++r) {
            const int co = m * 16 + row4 + r;
            const float bv = bias[co];
            #pragma unroll
            for (int nt = 0; nt < 2; ++nt) {
                const int wout = w0 + nt * 16 + col;
                out[((b * COUT + co) * HH + hout) * WW + wout] = acc[m][nt][r] * s + bv;
            }
        }
    }
}

extern "C" void kernel_launch(void* const* d_in, const int* in_sizes, int n_in,
                              void* d_out, int out_size, void* d_ws, size_t ws_size,
                              hipStream_t stream) {
    const float* x    = (const float*)d_in[0];
    const float* wgt  = (const float*)d_in[1];
    const float* bias = (const float*)d_in[2];
    float* out        = (float*)d_out;
    unsigned* ws      = (unsigned*)d_ws;

    hipMemsetAsync(d_ws, 0, 16, stream);
    const int n4 = in_sizes[0] / 4;                       // 12845056 / 4
    k_prep<<<RED_BLOCKS + 1, 256, 0, stream>>>(x, n4, wgt, ws);
    k_conv<<<NB * 56 * 7, 256, 0, stream>>>(x, bias, ws, out);
}

// Round 2
// 157.278 us; speedup vs baseline: 1.0675x; 1.0675x over previous
//
#include <hip/hip_runtime.h>
#include <hip/hip_bf16.h>
#include <stdint.h>

// QuantConv2d on MI355X.
// Pipeline: k_prep (max|x| + weight quant) -> k_quant (x -> padded NHWC bf16, exact
// IEEE div + rint, once per element) -> k_conv (implicit GEMM, MFMA bf16, direct
// global B-fragment loads from NHWC layout; no LDS, no divides).
// Exactness: quantized values are small ints (exact in bf16); fp32 accumulation of
// integer products bounded by 288*127^2 < 2^24 -> exact.

typedef short short8 __attribute__((ext_vector_type(8)));
typedef float f32x4  __attribute__((ext_vector_type(4)));

#define CIN   32
#define COUT  32
#define HH    224
#define WW    224
#define NB    8
#define KK    288            // 9 taps * 32 ci, k ordered (kh,kw,ci)
#define QMAXF 127.0f
#define PP    226            // padded spatial dim (1-px zero border)

#define RED_BLOCKS 1024
#define QX_OFF  32768                                    // byte offset of qx in ws
#define QX_BYTES ((size_t)NB * PP * PP * CIN * 2)        // 26,152,448
#define WS_NEED (QX_OFF + QX_BYTES)

// ws layout: ws[0]=bits of max|x| (atomicMax), ws[1]=bits of w_scale,
// (ushort*)(ws+4) = qw bf16 [COUT][9][32] (k=(kh*3+kw)*32+ci),
// byte QX_OFF: qx bf16 [NB][PP][PP][CIN] zero-padded NHWC.

__global__ __launch_bounds__(256) void k_prep(const float* __restrict__ x, int n4,
                                              const float* __restrict__ wgt,
                                              unsigned* __restrict__ ws) {
    const int tid = threadIdx.x;
    __shared__ float red[4];
    if (blockIdx.x < RED_BLOCKS) {
        const float4* x4 = (const float4*)x;
        float m = 0.f;
        for (int i = blockIdx.x * 256 + tid; i < n4; i += RED_BLOCKS * 256) {
            float4 v = x4[i];
            m = fmaxf(m, fmaxf(fmaxf(fabsf(v.x), fabsf(v.y)), fmaxf(fabsf(v.z), fabsf(v.w))));
        }
        #pragma unroll
        for (int off = 32; off >= 1; off >>= 1) m = fmaxf(m, __shfl_xor(m, off));
        if ((tid & 63) == 0) red[tid >> 6] = m;
        __syncthreads();
        if (tid == 0) {
            m = fmaxf(fmaxf(red[0], red[1]), fmaxf(red[2], red[3]));
            atomicMax(ws, __float_as_uint(m));   // all >=0: uint order == float order
        }
    } else {
        float m = 0.f;
        for (int i = tid; i < COUT * CIN * 9; i += 256) m = fmaxf(m, fabsf(wgt[i]));
        #pragma unroll
        for (int off = 32; off >= 1; off >>= 1) m = fmaxf(m, __shfl_xor(m, off));
        if ((tid & 63) == 0) red[tid >> 6] = m;
        __syncthreads();
        const float mw = fmaxf(fmaxf(red[0], red[1]), fmaxf(red[2], red[3]));
        const float wscale = mw / QMAXF;
        if (tid == 0) ws[1] = __float_as_uint(wscale);
        ushort* qw = (ushort*)(ws + 4);
        for (int e = tid; e < COUT * KK; e += 256) {
            const int co = e / KK, k = e % KK;
            const int t = k >> 5, ci = k & 31;
            const int kh = t / 3, kw = t % 3;
            const float v = wgt[((co * CIN + ci) * 3 + kh) * 3 + kw];
            float q = rintf(v / wscale);                  // IEEE div + half-even == jnp
            q = fminf(fmaxf(q, -QMAXF), QMAXF);
            qw[e] = (ushort)(__float_as_uint(q) >> 16);   // small ints: exact bf16
        }
    }
}

// x (NCHW fp32) -> qx (padded NHWC bf16). One int4 (8 ci at one pixel) per thread-iter.
__global__ __launch_bounds__(256) void k_quant(const float* __restrict__ x,
                                               const unsigned* __restrict__ ws,
                                               ushort* __restrict__ qx) {
    const float xscale = __uint_as_float(ws[0]) / QMAXF;
    const int total = NB * PP * PP * 4;                  // int4 count
    for (int o8 = blockIdx.x * 256 + threadIdx.x; o8 < total; o8 += gridDim.x * 256) {
        const int ci8 = o8 & 3;
        int t = o8 >> 2;
        const int wp = t % PP; t /= PP;
        const int hp = t % PP;
        const int b  = t / PP;
        union { ushort qs[8]; int4 v; } u;
        u.v = make_int4(0, 0, 0, 0);
        if (hp != 0 && hp != PP - 1 && wp != 0 && wp != PP - 1) {
            const float* xp = x + ((size_t)(b * CIN + ci8 * 8) * HH + (hp - 1)) * WW + (wp - 1);
            #pragma unroll
            for (int c = 0; c < 8; ++c) {
                const float v = xp[c * (HH * WW)];
                float q = rintf(v / xscale);              // exact IEEE div, half-even
                q = fminf(fmaxf(q, -QMAXF), QMAXF);
                u.qs[c] = (ushort)(__float_as_uint(q) >> 16);
            }
        }
        ((int4*)qx)[o8] = u.v;
    }
}

// Implicit-GEMM conv. Wave tile: 32 px (2 n-frags) x 32 cout (2 m-frags). 4 waves/block,
// independent (no LDS/sync). B-frags are contiguous 16B/lane loads from NHWC qx.
__global__ __launch_bounds__(256) void k_conv(const ushort* __restrict__ qx,
                                              const ushort* __restrict__ qw,
                                              const float* __restrict__ bias,
                                              const unsigned* __restrict__ ws,
                                              float* __restrict__ out) {
    const int tid  = threadIdx.x;
    const int lane = tid & 63;
    const int wv   = tid >> 6;
    const int tIdx = blockIdx.x * 4 + wv;        // [0, 8*224*7)
    const int w0   = (tIdx % 7) * 32;
    const int h    = (tIdx / 7) % HH;
    const int b    = tIdx / (7 * HH);
    const int col  = lane & 15;
    const int kgrp = lane >> 4;

    const float xscale = __uint_as_float(ws[0]) / QMAXF;
    const float s = xscale * __uint_as_float(ws[1]);

    short8 afr[9][2];
    #pragma unroll
    for (int t = 0; t < 9; ++t)
        #pragma unroll
        for (int m = 0; m < 2; ++m)
            afr[t][m] = *(const short8*)&qw[((m * 16 + col) * 9 + t) * 32 + kgrp * 8];

    const f32x4 zero = {0.f, 0.f, 0.f, 0.f};
    f32x4 acc[2][2] = {{zero, zero}, {zero, zero}};

    // padded coords: hp = h + kh, wp = w + kw for w = w0 + nt*16 + col
    const ushort* base = qx + (((size_t)b * PP + h) * PP + (w0 + col)) * CIN + kgrp * 8;
    #pragma unroll
    for (int kh = 0; kh < 3; ++kh) {
        const ushort* rp = base + kh * PP * CIN;
        #pragma unroll
        for (int kw = 0; kw < 3; ++kw) {
            const int t = kh * 3 + kw;
            const short8 b0 = *(const short8*)(rp + kw * CIN);
            const short8 b1 = *(const short8*)(rp + kw * CIN + 16 * CIN);
            acc[0][0] = __builtin_amdgcn_mfma_f32_16x16x32_bf16(afr[t][0], b0, acc[0][0], 0, 0, 0);
            acc[1][0] = __builtin_amdgcn_mfma_f32_16x16x32_bf16(afr[t][1], b0, acc[1][0], 0, 0, 0);
            acc[0][1] = __builtin_amdgcn_mfma_f32_16x16x32_bf16(afr[t][0], b1, acc[0][1], 0, 0, 0);
            acc[1][1] = __builtin_amdgcn_mfma_f32_16x16x32_bf16(afr[t][1], b1, acc[1][1], 0, 0, 0);
        }
    }

    // D layout: col = lane&15 (pixel), row = kgrp*4 + reg (cout)
    const int hw = h * WW + w0 + col;
    #pragma unroll
    for (int m = 0; m < 2; ++m)
        #pragma unroll
        for (int r = 0; r < 4; ++r) {
            const int co = m * 16 + kgrp * 4 + r;
            const float bv = bias[co];
            float* op = out + (size_t)(b * COUT + co) * (HH * WW) + hw;
            op[0]  = acc[m][0][r] * s + bv;
            op[16] = acc[m][1][r] * s + bv;
        }
}

// ---- fallback path (R1 kernel, known-correct) if ws is too small for qx ----
#define RT  4
#define WT  32
#define XR  (RT + 2)
#define XW  (WT + 2)
#define CIP 40

__global__ __launch_bounds__(256) void k_conv_fb(const float* __restrict__ x,
                                                 const float* __restrict__ bias,
                                                 const unsigned* __restrict__ ws,
                                                 float* __restrict__ out) {
    __shared__ __align__(16) short xs[XR * XW * CIP];
    __shared__ __align__(16) short a_lds[COUT * KK];
    const int tid = threadIdx.x;
    const int bid = blockIdx.x;
    const int b   = bid / (56 * 7);
    const int rem = bid % (56 * 7);
    const int h0  = (rem / 7) * RT;
    const int w0  = (rem % 7) * WT;
    const float xscale = __uint_as_float(ws[0]) / QMAXF;
    const float wscale = __uint_as_float(ws[1]);
    const float s = xscale * wscale;
    {
        const int* qwi = (const int*)(ws + 4);
        int* ali = (int*)a_lds;
        #pragma unroll
        for (int i = 0; i < 18; ++i) ali[tid + 256 * i] = qwi[tid + 256 * i];
    }
    for (int i = 0; i < 26; ++i) {
        const int e = tid + 256 * i;
        if (e < XR * XW * CIN) {
            const int wl = e % XW;
            const int q2 = e / XW;
            const int ci = q2 & 31;
            const int r  = q2 >> 5;
            const int h  = h0 - 1 + r;
            const int wg = w0 - 1 + wl;
            float v = 0.f;
            if ((unsigned)h < HH && (unsigned)wg < WW)
                v = x[((b * CIN + ci) * HH + h) * WW + wg];
            float qv = rintf(v / xscale);
            qv = fminf(fmaxf(qv, -QMAXF), QMAXF);
            xs[(r * XW + wl) * CIP + ci] = (short)(__float_as_uint(qv) >> 16);
        }
    }
    __syncthreads();
    const int lane = tid & 63;
    const int wr   = tid >> 6;
    const int col  = lane & 15;
    const int kgrp = lane >> 4;
    short8 afr[9][2];
    #pragma unroll
    for (int t = 0; t < 9; ++t)
        #pragma unroll
        for (int m = 0; m < 2; ++m)
            afr[t][m] = *(const short8*)&a_lds[(m * 16 + col) * KK + t * 32 + kgrp * 8];
    const f32x4 zero = {0.f, 0.f, 0.f, 0.f};
    f32x4 acc[2][2] = {{zero, zero}, {zero, zero}};
    #pragma unroll
    for (int t = 0; t < 9; ++t) {
        const int kh = t / 3, kw = t % 3;
        short8 bfr[2];
        #pragma unroll
        for (int nt = 0; nt < 2; ++nt)
            bfr[nt] = *(const short8*)&xs[((wr + kh) * XW + (nt * 16 + col + kw)) * CIP + kgrp * 8];
        #pragma unroll
        for (int m = 0; m < 2; ++m)
            #pragma unroll
            for (int nt = 0; nt < 2; ++nt)
                acc[m][nt] = __builtin_amdgcn_mfma_f32_16x16x32_bf16(afr[t][m], bfr[nt], acc[m][nt], 0, 0, 0);
    }
    const int row4 = kgrp * 4;
    const int hout = h0 + wr;
    #pragma unroll
    for (int m = 0; m < 2; ++m)
        #pragma unroll
        for (int r = 0; r < 4; ++r) {
            const int co = m * 16 + row4 + r;
            const float bv = bias[co];
            #pragma unroll
            for (int nt = 0; nt < 2; ++nt)
                out[((b * COUT + co) * HH + hout) * WW + w0 + nt * 16 + col] = acc[m][nt][r] * s + bv;
        }
}

extern "C" void kernel_launch(void* const* d_in, const int* in_sizes, int n_in,
                              void* d_out, int out_size, void* d_ws, size_t ws_size,
                              hipStream_t stream) {
    const float* x    = (const float*)d_in[0];
    const float* wgt  = (const float*)d_in[1];
    const float* bias = (const float*)d_in[2];
    float* out        = (float*)d_out;
    unsigned* ws      = (unsigned*)d_ws;

    hipMemsetAsync(d_ws, 0, 16, stream);
    const int n4 = in_sizes[0] / 4;
    k_prep<<<RED_BLOCKS + 1, 256, 0, stream>>>(x, n4, wgt, ws);

    if (ws_size >= WS_NEED) {
        ushort* qx = (ushort*)((char*)d_ws + QX_OFF);
        ushort* qw = (ushort*)(ws + 4);
        k_quant<<<4096, 256, 0, stream>>>(x, ws, qx);
        k_conv<<<NB * HH * 7 / 4, 256, 0, stream>>>(qx, qw, bias, ws, out);
    } else {
        k_conv_fb<<<NB * 56 * 7, 256, 0, stream>>>(x, bias, ws, out);
    }
}

// Round 5
// 145.154 us; speedup vs baseline: 1.1567x; 1.0835x over previous
//
#include <hip/hip_runtime.h>
#include <hip/hip_bf16.h>
#include <stdint.h>

// QuantConv2d on MI355X.
// k_prep: per-block partial max|x| + weight quantization (exact IEEE div, half-even).
// k_quant: re-reduce partials -> xscale; x (NCHW f32) -> qx (padded NHWC bf16), exact.
// k_conv: implicit-GEMM 3x3 conv, bf16 MFMA, 2 output rows/wave with B-fragment reuse.
// Exactness: quantized values are small ints (exact in bf16); fp32 accumulation of
// integer products bounded by 288*127^2 < 2^24 -> exact.

typedef short short8 __attribute__((ext_vector_type(8)));
typedef float f32x4  __attribute__((ext_vector_type(4)));

#define CIN   32
#define COUT  32
#define HH    224
#define WW    224
#define NB    8
#define QMAXF 127.0f
#define PP    226            // padded spatial dim (1-px zero border)

#define RED_BLOCKS 1024
#define PF_OFF  16                                       // float idx of partial maxes
#define QW_OFF  8192                                     // byte offset of qw
#define QX_OFF  32768                                    // byte offset of qx
#define QX_BYTES ((size_t)NB * PP * PP * CIN * 2)        // 26,152,448 B

// ws layout: ws[0]=bits of xscale (written by k_quant blk0), ws[1]=bits of wscale,
// float ws[PF_OFF..PF_OFF+1024) = per-block partial max|x|,
// byte QW_OFF: qw bf16 [COUT][9][32] (k=(kh*3+kw)*32+ci),
// byte QX_OFF: qx bf16 [NB][PP][PP][CIN] zero-padded NHWC.

__global__ __launch_bounds__(256) void k_prep(const float* __restrict__ x, int n4,
                                              const float* __restrict__ wgt,
                                              unsigned* __restrict__ ws) {
    const int tid = threadIdx.x;
    __shared__ float red[4];
    if (blockIdx.x < RED_BLOCKS) {
        const float4* x4 = (const float4*)x;
        float m = 0.f;
        for (int i = blockIdx.x * 256 + tid; i < n4; i += RED_BLOCKS * 256) {
            float4 v = x4[i];
            m = fmaxf(m, fmaxf(fmaxf(fabsf(v.x), fabsf(v.y)), fmaxf(fabsf(v.z), fabsf(v.w))));
        }
        #pragma unroll
        for (int off = 32; off >= 1; off >>= 1) m = fmaxf(m, __shfl_xor(m, off));
        if ((tid & 63) == 0) red[tid >> 6] = m;
        __syncthreads();
        if (tid == 0)
            ((float*)ws)[PF_OFF + blockIdx.x] =
                fmaxf(fmaxf(red[0], red[1]), fmaxf(red[2], red[3]));
    } else {
        // single block: max|w| -> wscale, pre-quantize weights to bf16.
        float m = 0.f;
        for (int i = tid; i < COUT * CIN * 9; i += 256) m = fmaxf(m, fabsf(wgt[i]));
        #pragma unroll
        for (int off = 32; off >= 1; off >>= 1) m = fmaxf(m, __shfl_xor(m, off));
        if ((tid & 63) == 0) red[tid >> 6] = m;
        __syncthreads();
        const float mw = fmaxf(fmaxf(red[0], red[1]), fmaxf(red[2], red[3]));
        const float wscale = mw / QMAXF;
        if (tid == 0) ws[1] = __float_as_uint(wscale);
        ushort* qw = (ushort*)((char*)ws + QW_OFF);
        for (int e = tid; e < COUT * 288; e += 256) {
            const int co = e / 288, k = e % 288;
            const int t = k >> 5, ci = k & 31;
            const int kh = t / 3, kw = t % 3;
            const float v = wgt[((co * CIN + ci) * 3 + kh) * 3 + kw];
            float q = rintf(v / wscale);                  // IEEE div + half-even == jnp
            q = fminf(fmaxf(q, -QMAXF), QMAXF);
            qw[e] = (ushort)(__float_as_uint(q) >> 16);   // small ints: exact bf16
        }
    }
}

// x (NCHW fp32) -> qx (padded NHWC bf16). One int4 (8 ci at one pixel) per thread-iter.
__global__ __launch_bounds__(256) void k_quant(const float* __restrict__ x,
                                               unsigned* __restrict__ ws,
                                               ushort* __restrict__ qx) {
    // block-local re-reduction of the 1024 partial maxes (identical in every block)
    __shared__ float red[4];
    const float* pf = (const float*)ws + PF_OFF;
    float m = 0.f;
    for (int i = threadIdx.x; i < RED_BLOCKS; i += 256) m = fmaxf(m, pf[i]);
    #pragma unroll
    for (int off = 32; off >= 1; off >>= 1) m = fmaxf(m, __shfl_xor(m, off));
    if ((threadIdx.x & 63) == 0) red[threadIdx.x >> 6] = m;
    __syncthreads();
    const float xscale =
        fmaxf(fmaxf(red[0], red[1]), fmaxf(red[2], red[3])) / QMAXF;
    if (blockIdx.x == 0 && threadIdx.x == 0) ws[0] = __float_as_uint(xscale);

    const int total = NB * PP * PP * 4;                  // int4 count
    for (int o8 = blockIdx.x * 256 + threadIdx.x; o8 < total; o8 += gridDim.x * 256) {
        const int ci8 = o8 & 3;
        int t = o8 >> 2;
        const int wp = t % PP; t /= PP;
        const int hp = t % PP;
        const int b  = t / PP;
        union { ushort qs[8]; int4 v; } u;
        u.v = make_int4(0, 0, 0, 0);
        if (hp != 0 && hp != PP - 1 && wp != 0 && wp != PP - 1) {
            const float* xp = x + ((size_t)(b * CIN + ci8 * 8) * HH + (hp - 1)) * WW + (wp - 1);
            #pragma unroll
            for (int c = 0; c < 8; ++c) {
                const float v = xp[c * (HH * WW)];
                float q = rintf(v / xscale);              // exact IEEE div, half-even
                q = fminf(fmaxf(q, -QMAXF), QMAXF);
                u.qs[c] = (ushort)(__float_as_uint(q) >> 16);
            }
        }
        ((int4*)qx)[o8] = u.v;
    }
}

// Implicit-GEMM conv. Block = 1 w-tile (32 px) x 8 output rows; wave = 2 rows.
// Inner loop walks the 4 shared padded input rows; each loaded B-fragment feeds
// both output rows (3 MFMA per 16B load). No LDS, no divides, no branches.
__global__ __launch_bounds__(256) void k_conv(const ushort* __restrict__ qx,
                                              const ushort* __restrict__ qw,
                                              const float* __restrict__ bias,
                                              const unsigned* __restrict__ ws,
                                              float* __restrict__ out) {
    const int tid  = threadIdx.x;
    const int lane = tid & 63;
    const int wv   = tid >> 6;
    const int w0   = (blockIdx.x % 7) * 32;
    const int hb   = ((blockIdx.x / 7) % 28) * 8;
    const int b    = blockIdx.x / (7 * 28);
    const int h    = hb + wv * 2;                 // this wave's first output row
    const int col  = lane & 15;
    const int kgrp = lane >> 4;

    const float s = __uint_as_float(ws[0]) * __uint_as_float(ws[1]);

    short8 afr[9][2];
    #pragma unroll
    for (int t = 0; t < 9; ++t)
        #pragma unroll
        for (int m = 0; m < 2; ++m)
            afr[t][m] = *(const short8*)&qw[((m * 16 + col) * 9 + t) * 32 + kgrp * 8];

    const f32x4 zero = {0.f, 0.f, 0.f, 0.f};
    f32x4 acc[2][2][2];                            // [out-row][m][nt]
    #pragma unroll
    for (int o = 0; o < 2; ++o)
        #pragma unroll
        for (int m = 0; m < 2; ++m)
            #pragma unroll
            for (int nt = 0; nt < 2; ++nt) acc[o][m][nt] = zero;

    // padded row for (out h, kh) is h + kh; rows h..h+3 cover both output rows.
    const ushort* base = qx + (((size_t)b * PP + h) * PP + (w0 + col)) * CIN + kgrp * 8;
    #pragma unroll
    for (int pr = 0; pr < 4; ++pr) {
        #pragma unroll
        for (int kw = 0; kw < 3; ++kw) {
            const ushort* p = base + (pr * PP + kw) * CIN;
            const short8 b0 = *(const short8*)p;
            const short8 b1 = *(const short8*)(p + 16 * CIN);
            if (pr <= 2) {                          // out row h, kh = pr
                const int t = pr * 3 + kw;
                acc[0][0][0] = __builtin_amdgcn_mfma_f32_16x16x32_bf16(afr[t][0], b0, acc[0][0][0], 0, 0, 0);
                acc[0][1][0] = __builtin_amdgcn_mfma_f32_16x16x32_bf16(afr[t][1], b0, acc[0][1][0], 0, 0, 0);
                acc[0][0][1] = __builtin_amdgcn_mfma_f32_16x16x32_bf16(afr[t][0], b1, acc[0][0][1], 0, 0, 0);
                acc[0][1][1] = __builtin_amdgcn_mfma_f32_16x16x32_bf16(afr[t][1], b1, acc[0][1][1], 0, 0, 0);
            }
            if (pr >= 1) {                          // out row h+1, kh = pr-1
                const int t = (pr - 1) * 3 + kw;
                acc[1][0][0] = __builtin_amdgcn_mfma_f32_16x16x32_bf16(afr[t][0], b0, acc[1][0][0], 0, 0, 0);
                acc[1][1][0] = __builtin_amdgcn_mfma_f32_16x16x32_bf16(afr[t][1], b0, acc[1][1][0], 0, 0, 0);
                acc[1][0][1] = __builtin_amdgcn_mfma_f32_16x16x32_bf16(afr[t][0], b1, acc[1][0][1], 0, 0, 0);
                acc[1][1][1] = __builtin_amdgcn_mfma_f32_16x16x32_bf16(afr[t][1], b1, acc[1][1][1], 0, 0, 0);
            }
        }
    }

    // D layout: col = lane&15 (pixel), row = kgrp*4 + reg (cout)
    #pragma unroll
    for (int o = 0; o < 2; ++o) {
        const int hw = (h + o) * WW + w0 + col;
        #pragma unroll
        for (int m = 0; m < 2; ++m)
            #pragma unroll
            for (int r = 0; r < 4; ++r) {
                const int co = m * 16 + kgrp * 4 + r;
                const float bv = bias[co];
                float* op = out + (size_t)(b * COUT + co) * (HH * WW) + hw;
                op[0]  = acc[o][m][0][r] * s + bv;
                op[16] = acc[o][m][1][r] * s + bv;
            }
    }
}

extern "C" void kernel_launch(void* const* d_in, const int* in_sizes, int n_in,
                              void* d_out, int out_size, void* d_ws, size_t ws_size,
                              hipStream_t stream) {
    const float* x    = (const float*)d_in[0];
    const float* wgt  = (const float*)d_in[1];
    const float* bias = (const float*)d_in[2];
    float* out        = (float*)d_out;
    unsigned* ws      = (unsigned*)d_ws;
    ushort* qw        = (ushort*)((char*)d_ws + QW_OFF);
    ushort* qx        = (ushort*)((char*)d_ws + QX_OFF);

    const int n4 = in_sizes[0] / 4;
    k_prep <<<RED_BLOCKS + 1, 256, 0, stream>>>(x, n4, wgt, ws);
    k_quant<<<3200, 256, 0, stream>>>(x, ws, qx);
    k_conv <<<NB * 28 * 7, 256, 0, stream>>>(qx, qw, bias, ws, out);
}

// Round 7
// 132.176 us; speedup vs baseline: 1.2703x; 1.0982x over previous
//
#include <hip/hip_runtime.h>
#include <hip/hip_bf16.h>
#include <stdint.h>

// QuantConv2d on MI355X — int8 end-to-end.
// k_prep: per-block partial max|x| + weight quantization to int8 (exact IEEE div, half-even).
// k_quant: re-reduce partials -> xscale; x (NCHW f32) -> qx (padded NHWC int8), exact.
// k_conv: implicit-GEMM 3x3 conv, mfma_i32_32x32x32_i8 (one tap per MFMA), i32 accum.
// Exactness: q values are ints in [-127,127] (exact in i8); i32 accumulation is exact and
// equals the reference's fp32 einsum since every partial sum < 2^24.

typedef int i32x4  __attribute__((ext_vector_type(4)));
typedef int i32x16 __attribute__((ext_vector_type(16)));

#define CIN   32
#define COUT  32
#define HH    224
#define WW    224
#define NB    8
#define QMAXF 127.0f
#define PP    226            // padded spatial dim (1-px zero border)

#define RED_BLOCKS 1024
#define PF_OFF  16                                       // float idx of partial maxes
#define QW_OFF  8192                                     // byte offset of qw (int8 [32][288])
#define QX_OFF  32768                                    // byte offset of qx (int8 NHWC padded)

// ws layout: ws[0]=bits of xscale (written by k_quant), ws[1]=bits of wscale,
// float ws[PF_OFF..PF_OFF+1024) = per-block partial max|x|,
// byte QW_OFF: qw int8 [COUT][9][32] (k=(kh*3+kw)*32+ci),
// byte QX_OFF: qx int8 [NB][PP][PP][CIN] zero-padded NHWC.

__global__ __launch_bounds__(256) void k_prep(const float* __restrict__ x, int n4,
                                              const float* __restrict__ wgt,
                                              unsigned* __restrict__ ws) {
    const int tid = threadIdx.x;
    __shared__ float red[4];
    if (blockIdx.x < RED_BLOCKS) {
        const float4* x4 = (const float4*)x;
        float m = 0.f;
        for (int i = blockIdx.x * 256 + tid; i < n4; i += RED_BLOCKS * 256) {
            float4 v = x4[i];
            m = fmaxf(m, fmaxf(fmaxf(fabsf(v.x), fabsf(v.y)), fmaxf(fabsf(v.z), fabsf(v.w))));
        }
        #pragma unroll
        for (int off = 32; off >= 1; off >>= 1) m = fmaxf(m, __shfl_xor(m, off));
        if ((tid & 63) == 0) red[tid >> 6] = m;
        __syncthreads();
        if (tid == 0)
            ((float*)ws)[PF_OFF + blockIdx.x] =
                fmaxf(fmaxf(red[0], red[1]), fmaxf(red[2], red[3]));
    } else {
        // single block: max|w| -> wscale, pre-quantize weights to int8.
        float m = 0.f;
        for (int i = tid; i < COUT * CIN * 9; i += 256) m = fmaxf(m, fabsf(wgt[i]));
        #pragma unroll
        for (int off = 32; off >= 1; off >>= 1) m = fmaxf(m, __shfl_xor(m, off));
        if ((tid & 63) == 0) red[tid >> 6] = m;
        __syncthreads();
        const float mw = fmaxf(fmaxf(red[0], red[1]), fmaxf(red[2], red[3]));
        const float wscale = mw / QMAXF;
        if (tid == 0) ws[1] = __float_as_uint(wscale);
        signed char* qw = (signed char*)ws + QW_OFF;
        for (int e = tid; e < COUT * 288; e += 256) {
            const int co = e / 288, k = e % 288;
            const int t = k >> 5, ci = k & 31;
            const int kh = t / 3, kw = t % 3;
            const float v = wgt[((co * CIN + ci) * 3 + kh) * 3 + kw];
            float q = rintf(v / wscale);                  // IEEE div + half-even == jnp
            q = fminf(fmaxf(q, -QMAXF), QMAXF);
            qw[e] = (signed char)(int)q;                  // exact small int
        }
    }
}

// x (NCHW fp32) -> qx (padded NHWC int8). One int4 (16 ci at one pixel) per thread-iter.
__global__ __launch_bounds__(256) void k_quant(const float* __restrict__ x,
                                               unsigned* __restrict__ ws,
                                               signed char* __restrict__ qx) {
    // block-local re-reduction of the 1024 partial maxes (identical in every block)
    __shared__ float red[4];
    const float* pf = (const float*)ws + PF_OFF;
    float m = 0.f;
    for (int i = threadIdx.x; i < RED_BLOCKS; i += 256) m = fmaxf(m, pf[i]);
    #pragma unroll
    for (int off = 32; off >= 1; off >>= 1) m = fmaxf(m, __shfl_xor(m, off));
    if ((threadIdx.x & 63) == 0) red[threadIdx.x >> 6] = m;
    __syncthreads();
    const float xscale =
        fmaxf(fmaxf(red[0], red[1]), fmaxf(red[2], red[3])) / QMAXF;
    if (blockIdx.x == 0 && threadIdx.x == 0) ws[0] = __float_as_uint(xscale);

    const int total = NB * PP * PP * 2;                  // int4 (16-byte) stores
    for (int o16 = blockIdx.x * 256 + threadIdx.x; o16 < total; o16 += gridDim.x * 256) {
        const int half = o16 & 1;
        int t = o16 >> 1;
        const int wp = t % PP; t /= PP;
        const int hp = t % PP;
        const int b  = t / PP;
        union { signed char c[16]; int4 v; } u;
        u.v = make_int4(0, 0, 0, 0);
        if (hp != 0 && hp != PP - 1 && wp != 0 && wp != PP - 1) {
            const float* xp =
                x + ((size_t)(b * CIN + half * 16) * HH + (hp - 1)) * WW + (wp - 1);
            #pragma unroll
            for (int c = 0; c < 16; ++c) {
                const float v = xp[c * (HH * WW)];
                float q = rintf(v / xscale);              // exact IEEE div, half-even
                q = fminf(fmaxf(q, -QMAXF), QMAXF);
                u.c[c] = (signed char)(int)q;
            }
        }
        ((int4*)qx)[o16] = u.v;
    }
}

// Implicit-GEMM conv. Block = 1 w-tile (32 px) x 8 output rows; wave = 2 rows.
// mfma_i32_32x32x32_i8: one MFMA = 32co x 32px x one tap (32 ci).
// Inner loop walks 4 shared padded rows; each 16B B-load feeds up to 2 output rows.
// A frag: lane holds qw[co=lane&31][tap t][ci=(lane>>5)*16 + 0..15] (contiguous 16B).
// B frag: lane holds qx[row][px=w0+(lane&31)+kw][ci=(lane>>5)*16 + 0..15].
// C/D:    col(px)=lane&31, row(co)=(reg&3)+8*(reg>>2)+4*(lane>>5)  [guide m74/m101].
__global__ __launch_bounds__(256) void k_conv(const signed char* __restrict__ qx,
                                              const signed char* __restrict__ qw,
                                              const float* __restrict__ bias,
                                              const unsigned* __restrict__ ws,
                                              float* __restrict__ out) {
    const int tid  = threadIdx.x;
    const int lane = tid & 63;
    const int wv   = tid >> 6;
    const int w0   = (blockIdx.x % 7) * 32;
    const int hb   = ((blockIdx.x / 7) % 28) * 8;
    const int b    = blockIdx.x / (7 * 28);
    const int h    = hb + wv * 2;                 // this wave's first output row
    const int col  = lane & 31;                   // pixel for B/D, cout row for A
    const int hi   = lane >> 5;

    const float s = __uint_as_float(ws[0]) * __uint_as_float(ws[1]);

    i32x4 afr[9];
    #pragma unroll
    for (int t = 0; t < 9; ++t)
        afr[t] = *(const i32x4*)&qw[col * 288 + t * 32 + hi * 16];

    i32x16 acc0 = {0,0,0,0,0,0,0,0,0,0,0,0,0,0,0,0};
    i32x16 acc1 = {0,0,0,0,0,0,0,0,0,0,0,0,0,0,0,0};

    // padded row for (out h, kh) is h + kh; rows h..h+3 cover both output rows.
    const signed char* base =
        qx + (((size_t)b * PP + h) * PP + (w0 + col)) * CIN + hi * 16;
    #pragma unroll
    for (int pr = 0; pr < 4; ++pr) {
        #pragma unroll
        for (int kw = 0; kw < 3; ++kw) {
            const i32x4 bf = *(const i32x4*)(base + (pr * PP + kw) * CIN);
            if (pr <= 2)                          // out row h, kh = pr
                acc0 = __builtin_amdgcn_mfma_i32_32x32x32_i8(afr[pr * 3 + kw], bf, acc0, 0, 0, 0);
            if (pr >= 1)                          // out row h+1, kh = pr-1
                acc1 = __builtin_amdgcn_mfma_i32_32x32x32_i8(afr[(pr - 1) * 3 + kw], bf, acc1, 0, 0, 0);
        }
    }

    // epilogue: dequant + bias
    const size_t hw0 = (size_t)h * WW + w0 + col;
    #pragma unroll
    for (int r = 0; r < 16; ++r) {
        const int co = (r & 3) + 8 * (r >> 2) + 4 * hi;
        const float bv = bias[co];
        float* op = out + (size_t)(b * COUT + co) * (HH * WW) + hw0;
        op[0]  = (float)acc0[r] * s + bv;
        op[WW] = (float)acc1[r] * s + bv;
    }
}

extern "C" void kernel_launch(void* const* d_in, const int* in_sizes, int n_in,
                              void* d_out, int out_size, void* d_ws, size_t ws_size,
                              hipStream_t stream) {
    const float* x    = (const float*)d_in[0];
    const float* wgt  = (const float*)d_in[1];
    const float* bias = (const float*)d_in[2];
    float* out        = (float*)d_out;
    unsigned* ws      = (unsigned*)d_ws;
    const signed char* qw = (const signed char*)d_ws + QW_OFF;
    signed char* qx       = (signed char*)d_ws + QX_OFF;

    const int n4 = in_sizes[0] / 4;
    k_prep <<<RED_BLOCKS + 1, 256, 0, stream>>>(x, n4, wgt, ws);
    k_quant<<<3200, 256, 0, stream>>>(x, ws, qx);
    k_conv <<<NB * 28 * 7, 256, 0, stream>>>(qx, qw, bias, ws, out);
}